// Round 14
// baseline (147.642 us; speedup 1.0000x reference)
//
#include <hip/hip_runtime.h>
#include <cstdint>

#define B_ 32
#define F_ 256
#define T_ 4096
#define K_ 512
#define MT 128   // t-rows per block

typedef float f32x4 __attribute__((ext_vector_type(4)));
typedef __bf16 bf16x8 __attribute__((ext_vector_type(8)));

__device__ __forceinline__ unsigned short f2bf(float f) {
    union { float f; uint32_t u; } v; v.f = f;
    uint32_t u = v.u;
    uint32_t r = (u + 0x7FFFu + ((u >> 16) & 1u)) >> 16;
    return (unsigned short)r;
}

// LDS A-tile row swizzle: byte_off ^= ((row ^ (row>>3)) & 7) << 4  (bijective,
// floor-conflict on both the 16-rows-per-lane reads and 4-consec-row writes)
__device__ __forceinline__ int rowxor(int row) {
    return ((row ^ (row >> 3)) & 7) << 4;
}

// Kernel 1: emb [K,F] fp32 -> emb_bf [K,F] bf16, c_sq[K] = sum_f emb^2 (fp32)
__global__ __launch_bounds__(256)
void vq_prep(const float* __restrict__ emb, unsigned short* __restrict__ emb_bf,
             float* __restrict__ c_sq) {
    const int row  = blockIdx.x * 4 + (threadIdx.x >> 6);
    const int lane = threadIdx.x & 63;
    float4 v = *reinterpret_cast<const float4*>(emb + (size_t)row * F_ + lane * 4);
    ushort4 o;
    o.x = f2bf(v.x); o.y = f2bf(v.y); o.z = f2bf(v.z); o.w = f2bf(v.w);
    *reinterpret_cast<ushort4*>(emb_bf + (size_t)row * F_ + lane * 4) = o;
    float s = v.x*v.x + v.y*v.y + v.z*v.z + v.w*v.w;
    #pragma unroll
    for (int off = 32; off >= 1; off >>= 1) s += __shfl_xor(s, off);
    if (lane == 0) c_sq[row] = s;
}

// Main kernel: block = 128 t x 512 k; 512 threads = 8 waves (wt in {0,1} t-half,
// wk in {0..3} k-strip). FOUR k-quarters, swapped mfma, acc[2][4] (32 AGPR).
// In quarter q, wave (wt,wk) owns k [q*128 + wk*32, +32) x t [wt*64, +64).
// Lane (r,g): k = kq + m*16 + g*4 + e, t = t0 + wt*64 + n*16 + r.
__global__ __launch_bounds__(512, 4)
void vq_main(const float* __restrict__ x, const float* __restrict__ emb,
             const unsigned short* __restrict__ emb_bf, const float* __restrict__ c_sq,
             float* __restrict__ quant, float* __restrict__ dist) {
    __shared__ __attribute__((aligned(16))) unsigned short lds_a[MT * 256]; // 64 KB
    __shared__ float lds_part[16][MT];   // 8 KB; dead after xsq reduce -> reused as mv/mk
    __shared__ float lds_xsq[MT];
    __shared__ int   lds_idx[MT];

    float (*lds_mv)[MT] = (float(*)[MT])&lds_part[0][0];   // [4][128] overlays part[0..3]
    int   (*lds_mk)[MT] = (int  (*)[MT])&lds_part[4][0];   // [4][128] overlays part[4..7]

    const int tid = threadIdx.x;
    const int b   = blockIdx.y;
    const int t0  = blockIdx.x * MT;
    const float* xb = x + (size_t)b * (F_ * (size_t)T_);

    // ---- stage A: fp32 [F][t] -> bf16 LDS [t][F] via 4x4 register transpose ----
    {
        const int t4 = tid & 31;   // t-quad 0..31
        const int fx = tid >> 5;   // 0..15
        float xs[4] = {0.f, 0.f, 0.f, 0.f};
        #pragma unroll
        for (int it = 0; it < 4; ++it) {
            const int fq = fx + it * 16;     // f-quad 0..63
            const float* p = xb + (size_t)(fq * 4) * T_ + t0 + t4 * 4;
            f32x4 v0 = *reinterpret_cast<const f32x4*>(p);
            f32x4 v1 = *reinterpret_cast<const f32x4*>(p + T_);
            f32x4 v2 = *reinterpret_cast<const f32x4*>(p + 2 * (size_t)T_);
            f32x4 v3 = *reinterpret_cast<const f32x4*>(p + 3 * (size_t)T_);
            float rv[4][4] = {{v0.x,v1.x,v2.x,v3.x},{v0.y,v1.y,v2.y,v3.y},
                              {v0.z,v1.z,v2.z,v3.z},{v0.w,v1.w,v2.w,v3.w}};
            #pragma unroll
            for (int tt = 0; tt < 4; ++tt) {
                ushort4 pk;
                pk.x = f2bf(rv[tt][0]); pk.y = f2bf(rv[tt][1]);
                pk.z = f2bf(rv[tt][2]); pk.w = f2bf(rv[tt][3]);
                const int t = t4 * 4 + tt;
                const int boff = t * 512 + ((fq * 8) ^ rowxor(t));
                *reinterpret_cast<ushort4*>((char*)lds_a + boff) = pk;
                xs[tt] += rv[tt][0]*rv[tt][0] + rv[tt][1]*rv[tt][1]
                        + rv[tt][2]*rv[tt][2] + rv[tt][3]*rv[tt][3];
            }
        }
        #pragma unroll
        for (int tt = 0; tt < 4; ++tt) lds_part[fx][t4 * 4 + tt] = xs[tt];
    }
    __syncthreads();
    if (tid < MT) {
        float s = 0.f;
        #pragma unroll
        for (int p = 0; p < 16; ++p) s += lds_part[p][tid];
        lds_xsq[tid] = s;
    }
    __syncthreads();

    // ---- MFMA phase: 4 k-quarters, swapped operands, acc[2][4] (32 AGPR) ----
    const int w    = tid >> 6;      // wave 0..7
    const int wk   = w & 3;         // k-strip
    const int wt   = w >> 2;        // t-half
    const int lane = tid & 63;
    const int r    = lane & 15;
    const int g    = lane >> 4;

    float* distB = dist + ((size_t)b * T_ + t0) * K_;

    #pragma unroll
    for (int q = 0; q < 4; ++q) {
        f32x4 acc[2][4];   // [m over k][n over t]
        #pragma unroll
        for (int m = 0; m < 2; ++m)
            #pragma unroll
            for (int n = 0; n < 4; ++n) acc[m][n] = (f32x4){0.f, 0.f, 0.f, 0.f};

        const int kq = q * 128 + wk * 32;
        const unsigned short* Bb = emb_bf + (size_t)(kq + r) * F_ + g * 8;

        #pragma unroll
        for (int s = 0; s < 8; ++s) {
            bf16x8 ef[2], xf[4];
            #pragma unroll
            for (int m = 0; m < 2; ++m)   // emb fragments (k rows)
                ef[m] = *reinterpret_cast<const bf16x8*>(Bb + (size_t)m * 16 * F_ + s * 32);
            #pragma unroll
            for (int n = 0; n < 4; ++n) { // x fragments (t rows) from LDS
                const int arow = wt * 64 + n * 16 + r;
                xf[n] = *reinterpret_cast<const bf16x8*>(
                    (const char*)lds_a + arow * 512 + (((s * 64 + g * 16) ^ rowxor(arow))));
            }
            #pragma unroll
            for (int m = 0; m < 2; ++m)
                #pragma unroll
                for (int n = 0; n < 4; ++n)
                    acc[m][n] = __builtin_amdgcn_mfma_f32_16x16x32_bf16(ef[m], xf[n], acc[m][n], 0, 0, 0);
        }

        // epilogue: lane (r,g) holds k = kq+m*16+g*4+e, t = t0+wt*64+n*16+r
        f32x4 cs[2];
        #pragma unroll
        for (int m = 0; m < 2; ++m)
            cs[m] = *reinterpret_cast<const f32x4*>(&c_sq[kq + m * 16 + g * 4]);

        #pragma unroll
        for (int n = 0; n < 4; ++n) {
            const int tl = wt * 64 + n * 16 + r;
            const float xq = lds_xsq[tl];
            float* drow = distB + (size_t)tl * K_ + kq + g * 4;
            float v = 3.402823466e+38f; int k = 0;
            #pragma unroll
            for (int m = 0; m < 2; ++m) {
                f32x4 dv;
                #pragma unroll
                for (int e = 0; e < 4; ++e) {
                    const float d = fmaf(-2.0f, acc[m][n][e], xq + cs[m][e]);
                    dv[e] = d;
                    if (d < v) { v = d; k = kq + m * 16 + g * 4 + e; }
                }
                *reinterpret_cast<f32x4*>(drow + m * 16) = dv;   // through L2 (write-combine)
            }
            // reduce over the 4 g-lanes holding the same t (xor 16, 32)
            #pragma unroll
            for (int off = 16; off <= 32; off <<= 1) {
                float ov = __shfl_xor(v, off);
                int   ok = __shfl_xor(k, off);
                if (ov < v || (ov == v && ok < k)) { v = ov; k = ok; }
            }
            if (g == 0) {
                if (q == 0) {
                    lds_mv[wk][tl] = v; lds_mk[wk][tl] = k;
                } else {
                    float pv = lds_mv[wk][tl];
                    if (v < pv) { lds_mv[wk][tl] = v; lds_mk[wk][tl] = k; }
                }
            }
        }
    }

    __syncthreads();
    if (tid < MT) {
        float bv = lds_mv[0][tid]; int bk = lds_mk[0][tid];
        #pragma unroll
        for (int ww = 1; ww < 4; ++ww) {
            float v = lds_mv[ww][tid]; int k = lds_mk[ww][tid];
            if (v < bv || (v == bv && k < bk)) { bv = v; bk = k; }
        }
        lds_idx[tid] = bk;
    }
    __syncthreads();

    // ---- quant: quant[b][f][t0+tt] = emb[idx[tt]][f], coalesced along t ----
    const int tt  = tid & 127;
    const int fc0 = tid >> 7;    // 0..3
    const int myidx = lds_idx[tt];
    const float* erow = emb + (size_t)myidx * F_;
    float* qb = quant + (size_t)b * (F_ * (size_t)T_) + t0 + tt;
    #pragma unroll
    for (int it = 0; it < 16; ++it) {
        const int fc = fc0 + it * 4;
        float4 e = *reinterpret_cast<const float4*>(erow + fc * 4);
        qb[(size_t)(fc * 4 + 0) * T_] = e.x;
        qb[(size_t)(fc * 4 + 1) * T_] = e.y;
        qb[(size_t)(fc * 4 + 2) * T_] = e.z;
        qb[(size_t)(fc * 4 + 3) * T_] = e.w;
    }
}

extern "C" void kernel_launch(void* const* d_in, const int* in_sizes, int n_in,
                              void* d_out, int out_size, void* d_ws, size_t ws_size,
                              hipStream_t stream) {
    (void)in_sizes; (void)n_in; (void)out_size; (void)ws_size;
    const float* x   = (const float*)d_in[0];
    const float* emb = (const float*)d_in[1];
    float* out   = (float*)d_out;
    float* quant = out;                                   // [B,F,T]
    float* dist  = out + (size_t)B_ * F_ * T_;            // [B,T,K]
    unsigned short* emb_bf = (unsigned short*)d_ws;       // 256 KB
    float* c_sq = (float*)((char*)d_ws + (size_t)K_ * F_ * sizeof(unsigned short));

    vq_prep<<<dim3(K_ / 4), dim3(256), 0, stream>>>(emb, emb_bf, c_sq);
    vq_main<<<dim3(T_ / MT, B_), dim3(512), 0, stream>>>(x, emb, emb_bf, c_sq, quant, dist);
}

// Round 15
// 130.940 us; speedup vs baseline: 1.1275x; 1.1275x over previous
//
#include <hip/hip_runtime.h>
#include <cstdint>

#define B_ 32
#define F_ 256
#define T_ 4096
#define K_ 512
#define MT 128   // t-rows per block

typedef float f32x4 __attribute__((ext_vector_type(4)));
typedef __bf16 bf16x8 __attribute__((ext_vector_type(8)));

__device__ __forceinline__ unsigned short f2bf(float f) {
    union { float f; uint32_t u; } v; v.f = f;
    uint32_t u = v.u;
    uint32_t r = (u + 0x7FFFu + ((u >> 16) & 1u)) >> 16;
    return (unsigned short)r;
}

// LDS A-tile row swizzle: byte_off ^= ((row ^ (row>>3)) & 7) << 4  (bijective,
// floor-conflict on both the 16-rows-per-lane reads and 4-consec-row writes)
__device__ __forceinline__ int rowxor(int row) {
    return ((row ^ (row >> 3)) & 7) << 4;
}

// Kernel 1: emb [K,F] fp32 -> emb_bf [K,F] bf16, c_sq[K] = sum_f emb^2 (fp32)
__global__ __launch_bounds__(256)
void vq_prep(const float* __restrict__ emb, unsigned short* __restrict__ emb_bf,
             float* __restrict__ c_sq) {
    const int row  = blockIdx.x * 4 + (threadIdx.x >> 6);
    const int lane = threadIdx.x & 63;
    float4 v = *reinterpret_cast<const float4*>(emb + (size_t)row * F_ + lane * 4);
    ushort4 o;
    o.x = f2bf(v.x); o.y = f2bf(v.y); o.z = f2bf(v.z); o.w = f2bf(v.w);
    *reinterpret_cast<ushort4*>(emb_bf + (size_t)row * F_ + lane * 4) = o;
    float s = v.x*v.x + v.y*v.y + v.z*v.z + v.w*v.w;
    #pragma unroll
    for (int off = 32; off >= 1; off >>= 1) s += __shfl_xor(s, off);
    if (lane == 0) c_sq[row] = s;
}

// Main kernel: block = 128 t x 512 k; 512 threads = 8 waves (wt in {0,1} t-half,
// wk in {0..3} k-strip). FOUR k-quarters, swapped mfma, acc[2][4] (32 AGPR).
// In quarter q, wave (wt,wk) owns k [q*128 + wk*32, +32) x t [wt*64, +64).
// Lane (r,g): k = kq + m*16 + g*4 + e, t = t0 + wt*64 + n*16 + r.
// Cache policy (isolated R11-R14): x loads NT (read-once), quant stores NT
// (512B-contiguous per instruction), dist stores PLAIN (64B fragments need
// L2 write-combining).
__global__ __launch_bounds__(512, 4)
void vq_main(const float* __restrict__ x, const float* __restrict__ emb,
             const unsigned short* __restrict__ emb_bf, const float* __restrict__ c_sq,
             float* __restrict__ quant, float* __restrict__ dist) {
    __shared__ __attribute__((aligned(16))) unsigned short lds_a[MT * 256]; // 64 KB
    __shared__ float lds_part[16][MT];   // 8 KB; dead after xsq reduce -> reused as mv/mk
    __shared__ float lds_xsq[MT];
    __shared__ int   lds_idx[MT];

    float (*lds_mv)[MT] = (float(*)[MT])&lds_part[0][0];   // [4][128] overlays part[0..3]
    int   (*lds_mk)[MT] = (int  (*)[MT])&lds_part[4][0];   // [4][128] overlays part[4..7]

    const int tid = threadIdx.x;
    const int b   = blockIdx.y;
    const int t0  = blockIdx.x * MT;
    const float* xb = x + (size_t)b * (F_ * (size_t)T_);

    // ---- stage A: fp32 [F][t] -> bf16 LDS [t][F] via 4x4 register transpose ----
    {
        const int t4 = tid & 31;   // t-quad 0..31
        const int fx = tid >> 5;   // 0..15
        float xs[4] = {0.f, 0.f, 0.f, 0.f};
        #pragma unroll
        for (int it = 0; it < 4; ++it) {
            const int fq = fx + it * 16;     // f-quad 0..63
            const float* p = xb + (size_t)(fq * 4) * T_ + t0 + t4 * 4;
            f32x4 v0 = __builtin_nontemporal_load(reinterpret_cast<const f32x4*>(p));
            f32x4 v1 = __builtin_nontemporal_load(reinterpret_cast<const f32x4*>(p + T_));
            f32x4 v2 = __builtin_nontemporal_load(reinterpret_cast<const f32x4*>(p + 2 * (size_t)T_));
            f32x4 v3 = __builtin_nontemporal_load(reinterpret_cast<const f32x4*>(p + 3 * (size_t)T_));
            float rv[4][4] = {{v0.x,v1.x,v2.x,v3.x},{v0.y,v1.y,v2.y,v3.y},
                              {v0.z,v1.z,v2.z,v3.z},{v0.w,v1.w,v2.w,v3.w}};
            #pragma unroll
            for (int tt = 0; tt < 4; ++tt) {
                ushort4 pk;
                pk.x = f2bf(rv[tt][0]); pk.y = f2bf(rv[tt][1]);
                pk.z = f2bf(rv[tt][2]); pk.w = f2bf(rv[tt][3]);
                const int t = t4 * 4 + tt;
                const int boff = t * 512 + ((fq * 8) ^ rowxor(t));
                *reinterpret_cast<ushort4*>((char*)lds_a + boff) = pk;
                xs[tt] += rv[tt][0]*rv[tt][0] + rv[tt][1]*rv[tt][1]
                        + rv[tt][2]*rv[tt][2] + rv[tt][3]*rv[tt][3];
            }
        }
        #pragma unroll
        for (int tt = 0; tt < 4; ++tt) lds_part[fx][t4 * 4 + tt] = xs[tt];
    }
    __syncthreads();
    if (tid < MT) {
        float s = 0.f;
        #pragma unroll
        for (int p = 0; p < 16; ++p) s += lds_part[p][tid];
        lds_xsq[tid] = s;
    }
    __syncthreads();

    // ---- MFMA phase: 4 k-quarters, swapped operands, acc[2][4] (32 AGPR) ----
    const int w    = tid >> 6;      // wave 0..7
    const int wk   = w & 3;         // k-strip
    const int wt   = w >> 2;        // t-half
    const int lane = tid & 63;
    const int r    = lane & 15;
    const int g    = lane >> 4;

    float* distB = dist + ((size_t)b * T_ + t0) * K_;

    #pragma unroll
    for (int q = 0; q < 4; ++q) {
        f32x4 acc[2][4];   // [m over k][n over t]
        #pragma unroll
        for (int m = 0; m < 2; ++m)
            #pragma unroll
            for (int n = 0; n < 4; ++n) acc[m][n] = (f32x4){0.f, 0.f, 0.f, 0.f};

        const int kq = q * 128 + wk * 32;
        const unsigned short* Bb = emb_bf + (size_t)(kq + r) * F_ + g * 8;

        #pragma unroll
        for (int s = 0; s < 8; ++s) {
            bf16x8 ef[2], xf[4];
            #pragma unroll
            for (int m = 0; m < 2; ++m)   // emb fragments (k rows)
                ef[m] = *reinterpret_cast<const bf16x8*>(Bb + (size_t)m * 16 * F_ + s * 32);
            #pragma unroll
            for (int n = 0; n < 4; ++n) { // x fragments (t rows) from LDS
                const int arow = wt * 64 + n * 16 + r;
                xf[n] = *reinterpret_cast<const bf16x8*>(
                    (const char*)lds_a + arow * 512 + (((s * 64 + g * 16) ^ rowxor(arow))));
            }
            #pragma unroll
            for (int m = 0; m < 2; ++m)
                #pragma unroll
                for (int n = 0; n < 4; ++n)
                    acc[m][n] = __builtin_amdgcn_mfma_f32_16x16x32_bf16(ef[m], xf[n], acc[m][n], 0, 0, 0);
        }

        // epilogue: lane (r,g) holds k = kq+m*16+g*4+e, t = t0+wt*64+n*16+r
        f32x4 cs[2];
        #pragma unroll
        for (int m = 0; m < 2; ++m)
            cs[m] = *reinterpret_cast<const f32x4*>(&c_sq[kq + m * 16 + g * 4]);

        #pragma unroll
        for (int n = 0; n < 4; ++n) {
            const int tl = wt * 64 + n * 16 + r;
            const float xq = lds_xsq[tl];
            float* drow = distB + (size_t)tl * K_ + kq + g * 4;
            float v = 3.402823466e+38f; int k = 0;
            #pragma unroll
            for (int m = 0; m < 2; ++m) {
                f32x4 dv;
                #pragma unroll
                for (int e = 0; e < 4; ++e) {
                    const float d = fmaf(-2.0f, acc[m][n][e], xq + cs[m][e]);
                    dv[e] = d;
                    if (d < v) { v = d; k = kq + m * 16 + g * 4 + e; }
                }
                *reinterpret_cast<f32x4*>(drow + m * 16) = dv;   // through L2 (write-combine)
            }
            // reduce over the 4 g-lanes holding the same t (xor 16, 32)
            #pragma unroll
            for (int off = 16; off <= 32; off <<= 1) {
                float ov = __shfl_xor(v, off);
                int   ok = __shfl_xor(k, off);
                if (ov < v || (ov == v && ok < k)) { v = ov; k = ok; }
            }
            if (g == 0) {
                if (q == 0) {
                    lds_mv[wk][tl] = v; lds_mk[wk][tl] = k;
                } else {
                    float pv = lds_mv[wk][tl];
                    if (v < pv) { lds_mv[wk][tl] = v; lds_mk[wk][tl] = k; }
                }
            }
        }
    }

    __syncthreads();
    if (tid < MT) {
        float bv = lds_mv[0][tid]; int bk = lds_mk[0][tid];
        #pragma unroll
        for (int ww = 1; ww < 4; ++ww) {
            float v = lds_mv[ww][tid]; int k = lds_mk[ww][tid];
            if (v < bv || (v == bv && k < bk)) { bv = v; bk = k; }
        }
        lds_idx[tid] = bk;
    }
    __syncthreads();

    // ---- quant: quant[b][f][t0+tt] = emb[idx[tt]][f], coalesced along t ----
    const int tt  = tid & 127;
    const int fc0 = tid >> 7;    // 0..3
    const int myidx = lds_idx[tt];
    const float* erow = emb + (size_t)myidx * F_;
    float* qb = quant + (size_t)b * (F_ * (size_t)T_) + t0 + tt;
    #pragma unroll
    for (int it = 0; it < 16; ++it) {
        const int fc = fc0 + it * 4;
        float4 e = *reinterpret_cast<const float4*>(erow + fc * 4);
        __builtin_nontemporal_store(e.x, qb + (size_t)(fc * 4 + 0) * T_);
        __builtin_nontemporal_store(e.y, qb + (size_t)(fc * 4 + 1) * T_);
        __builtin_nontemporal_store(e.z, qb + (size_t)(fc * 4 + 2) * T_);
        __builtin_nontemporal_store(e.w, qb + (size_t)(fc * 4 + 3) * T_);
    }
}

extern "C" void kernel_launch(void* const* d_in, const int* in_sizes, int n_in,
                              void* d_out, int out_size, void* d_ws, size_t ws_size,
                              hipStream_t stream) {
    (void)in_sizes; (void)n_in; (void)out_size; (void)ws_size;
    const float* x   = (const float*)d_in[0];
    const float* emb = (const float*)d_in[1];
    float* out   = (float*)d_out;
    float* quant = out;                                   // [B,F,T]
    float* dist  = out + (size_t)B_ * F_ * T_;            // [B,T,K]
    unsigned short* emb_bf = (unsigned short*)d_ws;       // 256 KB
    float* c_sq = (float*)((char*)d_ws + (size_t)K_ * F_ * sizeof(unsigned short));

    vq_prep<<<dim3(K_ / 4), dim3(256), 0, stream>>>(emb, emb_bf, c_sq);
    vq_main<<<dim3(T_ / MT, B_), dim3(512), 0, stream>>>(x, emb, emb_bf, c_sq, quant, dist);
}

// Round 16
// 130.914 us; speedup vs baseline: 1.1278x; 1.0002x over previous
//
#include <hip/hip_runtime.h>
#include <cstdint>

#define B_ 32
#define F_ 256
#define T_ 4096
#define K_ 512
#define MT 128   // t-rows per block

typedef float f32x4 __attribute__((ext_vector_type(4)));
typedef __bf16 bf16x8 __attribute__((ext_vector_type(8)));

__device__ __forceinline__ unsigned short f2bf(float f) {
    union { float f; uint32_t u; } v; v.f = f;
    uint32_t u = v.u;
    uint32_t r = (u + 0x7FFFu + ((u >> 16) & 1u)) >> 16;
    return (unsigned short)r;
}

// LDS A-tile row swizzle: byte_off ^= ((row ^ (row>>3)) & 7) << 4  (bijective,
// floor-conflict on both the 16-rows-per-lane reads and 4-consec-row writes)
__device__ __forceinline__ int rowxor(int row) {
    return ((row ^ (row >> 3)) & 7) << 4;
}

// Kernel 1: emb [K,F] fp32 -> emb_bf [K,F] bf16, c_sq[K] = sum_f emb^2 (fp32)
__global__ __launch_bounds__(256)
void vq_prep(const float* __restrict__ emb, unsigned short* __restrict__ emb_bf,
             float* __restrict__ c_sq) {
    const int row  = blockIdx.x * 4 + (threadIdx.x >> 6);
    const int lane = threadIdx.x & 63;
    float4 v = *reinterpret_cast<const float4*>(emb + (size_t)row * F_ + lane * 4);
    ushort4 o;
    o.x = f2bf(v.x); o.y = f2bf(v.y); o.z = f2bf(v.z); o.w = f2bf(v.w);
    *reinterpret_cast<ushort4*>(emb_bf + (size_t)row * F_ + lane * 4) = o;
    float s = v.x*v.x + v.y*v.y + v.z*v.z + v.w*v.w;
    #pragma unroll
    for (int off = 32; off >= 1; off >>= 1) s += __shfl_xor(s, off);
    if (lane == 0) c_sq[row] = s;
}

// Main kernel: block = 128 t x 512 k; 512 threads = 8 waves (wt in {0,1} t-half,
// wk in {0..3} k-strip). FOUR k-quarters, swapped mfma, acc[2][4] (32 AGPR).
// In quarter q, wave (wt,wk) owns k [q*128 + wk*32, +32) x t [wt*64, +64).
// Lane (r,g): k = kq + m*16 + g*4 + e, t = t0 + wt*64 + n*16 + r.
// Cache policy (isolated R11-R14): x loads NT (read-once), quant stores NT
// (512B-contiguous per instruction), dist stores PLAIN (64B fragments need
// L2 write-combining).
// Stage loop is 2-chunk software-pipelined to avoid per-chunk vmcnt(0) stalls.
__global__ __launch_bounds__(512, 4)
void vq_main(const float* __restrict__ x, const float* __restrict__ emb,
             const unsigned short* __restrict__ emb_bf, const float* __restrict__ c_sq,
             float* __restrict__ quant, float* __restrict__ dist) {
    __shared__ __attribute__((aligned(16))) unsigned short lds_a[MT * 256]; // 64 KB
    __shared__ float lds_part[16][MT];   // 8 KB; dead after xsq reduce -> reused as mv/mk
    __shared__ float lds_xsq[MT];
    __shared__ int   lds_idx[MT];

    float (*lds_mv)[MT] = (float(*)[MT])&lds_part[0][0];   // [4][128] overlays part[0..3]
    int   (*lds_mk)[MT] = (int  (*)[MT])&lds_part[4][0];   // [4][128] overlays part[4..7]

    const int tid = threadIdx.x;
    const int b   = blockIdx.y;
    const int t0  = blockIdx.x * MT;
    const float* xb = x + (size_t)b * (F_ * (size_t)T_);

    // ---- stage A: fp32 [F][t] -> bf16 LDS [t][F], 2-deep pipelined chunks ----
    {
        const int t4 = tid & 31;   // t-quad 0..31
        const int fx = tid >> 5;   // 0..15
        float xs[4] = {0.f, 0.f, 0.f, 0.f};

        f32x4 bufA[4], bufB[4];
        const float* pbase = xb + t0 + t4 * 4;

        #define ISSUE(buf, it)                                                      \
            {                                                                       \
                const float* p = pbase + (size_t)((fx + (it) * 16) * 4) * T_;       \
                buf[0] = __builtin_nontemporal_load(reinterpret_cast<const f32x4*>(p));              \
                buf[1] = __builtin_nontemporal_load(reinterpret_cast<const f32x4*>(p + T_));         \
                buf[2] = __builtin_nontemporal_load(reinterpret_cast<const f32x4*>(p + 2 * (size_t)T_)); \
                buf[3] = __builtin_nontemporal_load(reinterpret_cast<const f32x4*>(p + 3 * (size_t)T_)); \
            }
        #define PROCESS(buf, it)                                                    \
            {                                                                       \
                const int fq = fx + (it) * 16;                                      \
                float rv[4][4] = {{buf[0].x,buf[1].x,buf[2].x,buf[3].x},            \
                                  {buf[0].y,buf[1].y,buf[2].y,buf[3].y},            \
                                  {buf[0].z,buf[1].z,buf[2].z,buf[3].z},            \
                                  {buf[0].w,buf[1].w,buf[2].w,buf[3].w}};           \
                _Pragma("unroll")                                                   \
                for (int tt = 0; tt < 4; ++tt) {                                    \
                    ushort4 pk;                                                     \
                    pk.x = f2bf(rv[tt][0]); pk.y = f2bf(rv[tt][1]);                 \
                    pk.z = f2bf(rv[tt][2]); pk.w = f2bf(rv[tt][3]);                 \
                    const int t = t4 * 4 + tt;                                      \
                    const int boff = t * 512 + (((fq) * 8) ^ rowxor(t));            \
                    *reinterpret_cast<ushort4*>((char*)lds_a + boff) = pk;          \
                    xs[tt] += rv[tt][0]*rv[tt][0] + rv[tt][1]*rv[tt][1]             \
                            + rv[tt][2]*rv[tt][2] + rv[tt][3]*rv[tt][3];            \
                }                                                                   \
            }

        ISSUE(bufA, 0);
        ISSUE(bufB, 1);
        PROCESS(bufA, 0);
        ISSUE(bufA, 2);
        PROCESS(bufB, 1);
        ISSUE(bufB, 3);
        PROCESS(bufA, 2);
        PROCESS(bufB, 3);
        #undef ISSUE
        #undef PROCESS

        #pragma unroll
        for (int tt = 0; tt < 4; ++tt) lds_part[fx][t4 * 4 + tt] = xs[tt];
    }
    __syncthreads();
    if (tid < MT) {
        float s = 0.f;
        #pragma unroll
        for (int p = 0; p < 16; ++p) s += lds_part[p][tid];
        lds_xsq[tid] = s;
    }
    __syncthreads();

    // ---- MFMA phase: 4 k-quarters, swapped operands, acc[2][4] (32 AGPR) ----
    const int w    = tid >> 6;      // wave 0..7
    const int wk   = w & 3;         // k-strip
    const int wt   = w >> 2;        // t-half
    const int lane = tid & 63;
    const int r    = lane & 15;
    const int g    = lane >> 4;

    float* distB = dist + ((size_t)b * T_ + t0) * K_;

    #pragma unroll
    for (int q = 0; q < 4; ++q) {
        f32x4 acc[2][4];   // [m over k][n over t]
        #pragma unroll
        for (int m = 0; m < 2; ++m)
            #pragma unroll
            for (int n = 0; n < 4; ++n) acc[m][n] = (f32x4){0.f, 0.f, 0.f, 0.f};

        const int kq = q * 128 + wk * 32;
        const unsigned short* Bb = emb_bf + (size_t)(kq + r) * F_ + g * 8;

        #pragma unroll
        for (int s = 0; s < 8; ++s) {
            bf16x8 ef[2], xf[4];
            #pragma unroll
            for (int m = 0; m < 2; ++m)   // emb fragments (k rows)
                ef[m] = *reinterpret_cast<const bf16x8*>(Bb + (size_t)m * 16 * F_ + s * 32);
            #pragma unroll
            for (int n = 0; n < 4; ++n) { // x fragments (t rows) from LDS
                const int arow = wt * 64 + n * 16 + r;
                xf[n] = *reinterpret_cast<const bf16x8*>(
                    (const char*)lds_a + arow * 512 + (((s * 64 + g * 16) ^ rowxor(arow))));
            }
            #pragma unroll
            for (int m = 0; m < 2; ++m)
                #pragma unroll
                for (int n = 0; n < 4; ++n)
                    acc[m][n] = __builtin_amdgcn_mfma_f32_16x16x32_bf16(ef[m], xf[n], acc[m][n], 0, 0, 0);
        }

        // epilogue: lane (r,g) holds k = kq+m*16+g*4+e, t = t0+wt*64+n*16+r
        f32x4 cs[2];
        #pragma unroll
        for (int m = 0; m < 2; ++m)
            cs[m] = *reinterpret_cast<const f32x4*>(&c_sq[kq + m * 16 + g * 4]);

        #pragma unroll
        for (int n = 0; n < 4; ++n) {
            const int tl = wt * 64 + n * 16 + r;
            const float xq = lds_xsq[tl];
            float* drow = distB + (size_t)tl * K_ + kq + g * 4;
            float v = 3.402823466e+38f; int k = 0;
            #pragma unroll
            for (int m = 0; m < 2; ++m) {
                f32x4 dv;
                #pragma unroll
                for (int e = 0; e < 4; ++e) {
                    const float d = fmaf(-2.0f, acc[m][n][e], xq + cs[m][e]);
                    dv[e] = d;
                    if (d < v) { v = d; k = kq + m * 16 + g * 4 + e; }
                }
                *reinterpret_cast<f32x4*>(drow + m * 16) = dv;   // through L2 (write-combine)
            }
            // reduce over the 4 g-lanes holding the same t (xor 16, 32)
            #pragma unroll
            for (int off = 16; off <= 32; off <<= 1) {
                float ov = __shfl_xor(v, off);
                int   ok = __shfl_xor(k, off);
                if (ov < v || (ov == v && ok < k)) { v = ov; k = ok; }
            }
            if (g == 0) {
                if (q == 0) {
                    lds_mv[wk][tl] = v; lds_mk[wk][tl] = k;
                } else {
                    float pv = lds_mv[wk][tl];
                    if (v < pv) { lds_mv[wk][tl] = v; lds_mk[wk][tl] = k; }
                }
            }
        }
    }

    __syncthreads();
    if (tid < MT) {
        float bv = lds_mv[0][tid]; int bk = lds_mk[0][tid];
        #pragma unroll
        for (int ww = 1; ww < 4; ++ww) {
            float v = lds_mv[ww][tid]; int k = lds_mk[ww][tid];
            if (v < bv || (v == bv && k < bk)) { bv = v; bk = k; }
        }
        lds_idx[tid] = bk;
    }
    __syncthreads();

    // ---- quant: quant[b][f][t0+tt] = emb[idx[tt]][f], coalesced along t ----
    const int tt  = tid & 127;
    const int fc0 = tid >> 7;    // 0..3
    const int myidx = lds_idx[tt];
    const float* erow = emb + (size_t)myidx * F_;
    float* qb = quant + (size_t)b * (F_ * (size_t)T_) + t0 + tt;
    #pragma unroll
    for (int it = 0; it < 16; ++it) {
        const int fc = fc0 + it * 4;
        float4 e = *reinterpret_cast<const float4*>(erow + fc * 4);
        __builtin_nontemporal_store(e.x, qb + (size_t)(fc * 4 + 0) * T_);
        __builtin_nontemporal_store(e.y, qb + (size_t)(fc * 4 + 1) * T_);
        __builtin_nontemporal_store(e.z, qb + (size_t)(fc * 4 + 2) * T_);
        __builtin_nontemporal_store(e.w, qb + (size_t)(fc * 4 + 3) * T_);
    }
}

extern "C" void kernel_launch(void* const* d_in, const int* in_sizes, int n_in,
                              void* d_out, int out_size, void* d_ws, size_t ws_size,
                              hipStream_t stream) {
    (void)in_sizes; (void)n_in; (void)out_size; (void)ws_size;
    const float* x   = (const float*)d_in[0];
    const float* emb = (const float*)d_in[1];
    float* out   = (float*)d_out;
    float* quant = out;                                   // [B,F,T]
    float* dist  = out + (size_t)B_ * F_ * T_;            // [B,T,K]
    unsigned short* emb_bf = (unsigned short*)d_ws;       // 256 KB
    float* c_sq = (float*)((char*)d_ws + (size_t)K_ * F_ * sizeof(unsigned short));

    vq_prep<<<dim3(K_ / 4), dim3(256), 0, stream>>>(emb, emb_bf, c_sq);
    vq_main<<<dim3(T_ / MT, B_), dim3(512), 0, stream>>>(x, emb, emb_bf, c_sq, quant, dist);
}